// Round 1
// baseline (3217.621 us; speedup 1.0000x reference)
//
#include <hip/hip_runtime.h>
#include <hip/hip_bf16.h>

#define BATCH (1u<<20)
static constexpr float EPSBN = 1e-5f;
static constexpr float INV_B = 1.0f / (float)BATCH;

// ws float-offsets for tables
#define TB1F 0
#define TT1F 1920
#define TB2F 3072
#define TT2F 4992
// ws byte-offsets
#define OFF_STATS  24576ULL           // 224 entries * 64B  (sum @+0, sq @+32B)
#define OFF_PARAMS 38912ULL           // 448 floats: sc1@0 sh1@128 sc2@256 sh2@320 sc3@384 sh3@416
#define OFF_X2     40960ULL           // f32 [64][B]
#define OFF_X3     (40960ULL + 268435456ULL)   // f32 [32][B]
#define WS_NEED    (40960ULL + 268435456ULL + 134217728ULL)

struct Ptrs {
  const int *br1,*sz1,*en1,*tp1; const float *ag1,*so1,*wt1;
  const int *br2,*sz2,*en2,*tp2; const float *ag2,*so2,*wt2;
  const float *bemb,*temb;
  const float *W1,*b1,*g1,*be1;
  const float *W2,*b2,*g2,*be2;
  const float *W3,*b3,*g3,*be3;
  const float *W4,*b4;
  float* ws; float* out;
};

struct SIn {
  int br1, sz1, en1, tp1, br2, sz2, en2, tp2;
  float na1, so1, nw1, na2, so2, nw2;
};

__device__ __forceinline__ float4 ld4(const float* p) {
  return *reinterpret_cast<const float4*>(p);
}
__device__ __forceinline__ void add4(float4& a, const float4 b) {
  a.x += b.x; a.y += b.y; a.z += b.z; a.w += b.w;
}
__device__ __forceinline__ void fma4s(float4& a, const float4 b, float s) {
  a.x = fmaf(b.x, s, a.x); a.y = fmaf(b.y, s, a.y);
  a.z = fmaf(b.z, s, a.z); a.w = fmaf(b.w, s, a.w);
}

__device__ __forceinline__ SIn load_sample(const Ptrs& P, unsigned s) {
  SIn si;
  si.br1 = P.br1[s]; si.sz1 = P.sz1[s]; si.en1 = P.en1[s]; si.tp1 = P.tp1[s];
  si.br2 = P.br2[s]; si.sz2 = P.sz2[s]; si.en2 = P.en2[s]; si.tp2 = P.tp2[s];
  si.na1 = P.ag1[s] * (1.0f/15.0f); si.so1 = P.so1[s]; si.nw1 = P.wt1[s] * 0.01f;
  si.na2 = P.ag2[s] * (1.0f/15.0f); si.so2 = P.so2[s]; si.nw2 = P.wt2[s] * 0.01f;
  return si;
}

// h1 chunk of 4 channels (BN1 + relu applied)
__device__ __forceinline__ float4 encode4(int c4, const SIn& si, const Ptrs& P,
                                          const float* sc1, const float* sh1) {
  const int c = c4 * 4;
  const float* ws = P.ws;
  float4 v = ld4(ws + TB1F + si.br1*128 + c);
  add4(v, ld4(ws + TT1F + si.tp1*128 + c));
  add4(v, ld4(ws + TB2F + si.br2*128 + c));
  add4(v, ld4(ws + TT2F + si.tp2*128 + c));
  add4(v, ld4(P.W1 + (8  + si.sz1)*128 + c));
  add4(v, ld4(P.W1 + (11 + si.en1)*128 + c));
  add4(v, ld4(P.W1 + (33 + si.sz2)*128 + c));
  add4(v, ld4(P.W1 + (36 + si.en2)*128 + c));
  fma4s(v, ld4(P.W1 + 22*128 + c), si.na1);
  fma4s(v, ld4(P.W1 + 23*128 + c), si.so1);
  fma4s(v, ld4(P.W1 + 24*128 + c), si.nw1);
  fma4s(v, ld4(P.W1 + 47*128 + c), si.na2);
  fma4s(v, ld4(P.W1 + 48*128 + c), si.so2);
  fma4s(v, ld4(P.W1 + 49*128 + c), si.nw2);
  const float4 sc = ld4(sc1 + c), sh = ld4(sh1 + c);
  float4 h;
  h.x = fmaxf(fmaf(v.x, sc.x, sh.x), 0.0f);
  h.y = fmaxf(fmaf(v.y, sc.y, sh.y), 0.0f);
  h.z = fmaxf(fmaf(v.z, sc.z, sh.z), 0.0f);
  h.w = fmaxf(fmaf(v.w, sc.w, sh.w), 0.0f);
  return h;
}

// x2[64] = h1 @ W2 + b2 (pre-BN2)
__device__ __forceinline__ void compute_x2(const SIn& si, const Ptrs& P,
                                           const float* sc1, const float* sh1,
                                           float4 acc[16]) {
  #pragma unroll
  for (int j4 = 0; j4 < 16; ++j4) acc[j4] = ld4(P.b2 + j4*4);
  #pragma unroll 1
  for (int c4 = 0; c4 < 32; ++c4) {
    const float4 h = encode4(c4, si, P, sc1, sh1);
    const float hr[4] = {h.x, h.y, h.z, h.w};
    #pragma unroll
    for (int r = 0; r < 4; ++r) {
      const int k = c4*4 + r;
      const float4* wrow = reinterpret_cast<const float4*>(P.W2 + k*64);
      #pragma unroll
      for (int j4 = 0; j4 < 16; ++j4) fma4s(acc[j4], wrow[j4], hr[r]);
    }
  }
}

// x3[32] = relu(BN2(x2)) @ W3 + b3 (pre-BN3), from register x2
__device__ __forceinline__ void x3_from_acc2(const float4 acc2[16], const Ptrs& P,
                                             const float* sc2, const float* sh2,
                                             float4 acc3[8]) {
  #pragma unroll
  for (int j4 = 0; j4 < 8; ++j4) acc3[j4] = ld4(P.b3 + j4*4);
  #pragma unroll
  for (int k4 = 0; k4 < 16; ++k4) {
    const float4 a = acc2[k4];
    const float4 sc = ld4(sc2 + k4*4), sh = ld4(sh2 + k4*4);
    const float hr[4] = {
      fmaxf(fmaf(a.x, sc.x, sh.x), 0.0f),
      fmaxf(fmaf(a.y, sc.y, sh.y), 0.0f),
      fmaxf(fmaf(a.z, sc.z, sh.z), 0.0f),
      fmaxf(fmaf(a.w, sc.w, sh.w), 0.0f)};
    #pragma unroll
    for (int r = 0; r < 4; ++r) {
      const int k = k4*4 + r;
      const float4* wrow = reinterpret_cast<const float4*>(P.W3 + k*32);
      #pragma unroll
      for (int j4 = 0; j4 < 8; ++j4) fma4s(acc3[j4], wrow[j4], hr[r]);
    }
  }
}

// wave transpose-reduce: after call, return on lane L = sum over 64 lanes of st_orig[L]
__device__ __forceinline__ float bfly_sum64(float st[64]) {
  const int lane = threadIdx.x & 63;
#define BSTEP(D) { const bool hi = (lane & D) != 0; \
  _Pragma("unroll") \
  for (int i = 0; i < D; ++i) { \
    float mine = hi ? st[i] : st[i+D]; \
    float oth  = __shfl_xor(mine, D, 64); \
    float keep = hi ? st[i+D] : st[i]; \
    st[i] = keep + oth; } }
  BSTEP(32) BSTEP(16) BSTEP(8) BSTEP(4) BSTEP(2) BSTEP(1)
#undef BSTEP
  return st[0];
}

// ---------------- kernels ----------------

__global__ __launch_bounds__(128) void k_tables(Ptrs P) {
  const int c = threadIdx.x;  // 0..127
  float* ws = P.ws;
  for (int b = 0; b < 15; ++b) {
    float a1 = P.b1[c], a2 = 0.0f;
    #pragma unroll
    for (int e = 0; e < 8; ++e) {
      a1 = fmaf(P.bemb[b*8+e], P.W1[e*128 + c], a1);
      a2 = fmaf(P.bemb[b*8+e], P.W1[(25+e)*128 + c], a2);
    }
    ws[TB1F + b*128 + c] = a1;
    ws[TB2F + b*128 + c] = a2;
  }
  for (int t = 0; t < 9; ++t) {
    float a1 = 0.0f, a2 = 0.0f;
    #pragma unroll
    for (int e = 0; e < 8; ++e) {
      a1 = fmaf(P.temb[t*8+e], P.W1[(14+e)*128 + c], a1);
      a2 = fmaf(P.temb[t*8+e], P.W1[(39+e)*128 + c], a2);
    }
    ws[TT1F + t*128 + c] = a1;
    ws[TT2F + t*128 + c] = a2;
  }
}

__global__ __launch_bounds__(256) void k_stats1(Ptrs P) {
  const int c = threadIdx.x & 127;
  const int half = threadIdx.x >> 7;
  const float* ws = P.ws;
  float fsum = 0.0f, fsq = 0.0f;
  for (unsigned s = blockIdx.x*2 + half; s < BATCH; s += gridDim.x*2) {
    const int br1 = P.br1[s], sz1 = P.sz1[s], en1 = P.en1[s], tp1 = P.tp1[s];
    const int br2 = P.br2[s], sz2 = P.sz2[s], en2 = P.en2[s], tp2 = P.tp2[s];
    const float na1 = P.ag1[s]*(1.0f/15.0f), so1 = P.so1[s], nw1 = P.wt1[s]*0.01f;
    const float na2 = P.ag2[s]*(1.0f/15.0f), so2 = P.so2[s], nw2 = P.wt2[s]*0.01f;
    float x = ws[TB1F + br1*128 + c] + ws[TT1F + tp1*128 + c]
            + ws[TB2F + br2*128 + c] + ws[TT2F + tp2*128 + c]
            + P.W1[(8+sz1)*128 + c] + P.W1[(11+en1)*128 + c]
            + P.W1[(33+sz2)*128 + c] + P.W1[(36+en2)*128 + c];
    x = fmaf(na1, P.W1[22*128 + c], x);
    x = fmaf(so1, P.W1[23*128 + c], x);
    x = fmaf(nw1, P.W1[24*128 + c], x);
    x = fmaf(na2, P.W1[47*128 + c], x);
    x = fmaf(so2, P.W1[48*128 + c], x);
    x = fmaf(nw2, P.W1[49*128 + c], x);
    fsum += x; fsq = fmaf(x, x, fsq);
  }
  __shared__ float red[512];
  red[threadIdx.x] = fsum; red[256 + threadIdx.x] = fsq;
  __syncthreads();
  if (threadIdx.x < 128) {
    float* stat = (float*)((char*)P.ws + OFF_STATS) + (size_t)c*16;
    atomicAdd(stat,     red[c] + red[c+128]);
    atomicAdd(stat + 8, red[256+c] + red[256+c+128]);
  }
}

__global__ void k_finalize(Ptrs P, int nch, int entry0, int pofs,
                           const float* g, const float* be) {
  const int c = threadIdx.x;
  if (c >= nch) return;
  const float* stat = (const float*)((const char*)P.ws + OFF_STATS) + (size_t)(entry0 + c)*16;
  const float mean = stat[0] * INV_B;
  const float var  = stat[8] * INV_B - mean*mean;
  const float inv  = 1.0f / sqrtf(var + EPSBN);
  const float scale = g[c] * inv;
  float* params = (float*)((char*)P.ws + OFF_PARAMS);
  params[pofs + c]       = scale;
  params[pofs + nch + c] = be[c] - mean * scale;
}

template<bool STORE>
__global__ __launch_bounds__(256) void k_layer2(Ptrs P) {
  const float* params = (const float*)((const char*)P.ws + OFF_PARAMS);
  const float* sc1 = params, *sh1 = params + 128;
  float psum = 0.0f, psq = 0.0f;  // per-lane: channel = lane
  const unsigned stride = gridDim.x * 256;
  for (unsigned s = blockIdx.x*256 + threadIdx.x; s < BATCH; s += stride) {
    const SIn si = load_sample(P, s);
    float4 acc[16];
    compute_x2(si, P, sc1, sh1, acc);
    if (STORE) {
      float* x2g = (float*)((char*)P.ws + OFF_X2);
      #pragma unroll
      for (int j4 = 0; j4 < 16; ++j4) {
        x2g[(size_t)(j4*4+0)*BATCH + s] = acc[j4].x;
        x2g[(size_t)(j4*4+1)*BATCH + s] = acc[j4].y;
        x2g[(size_t)(j4*4+2)*BATCH + s] = acc[j4].z;
        x2g[(size_t)(j4*4+3)*BATCH + s] = acc[j4].w;
      }
    }
    float st[64];
    #pragma unroll
    for (int j4 = 0; j4 < 16; ++j4) {
      st[4*j4+0] = acc[j4].x; st[4*j4+1] = acc[j4].y;
      st[4*j4+2] = acc[j4].z; st[4*j4+3] = acc[j4].w;
    }
    psum += bfly_sum64(st);
    #pragma unroll
    for (int j4 = 0; j4 < 16; ++j4) {
      st[4*j4+0] = acc[j4].x*acc[j4].x; st[4*j4+1] = acc[j4].y*acc[j4].y;
      st[4*j4+2] = acc[j4].z*acc[j4].z; st[4*j4+3] = acc[j4].w*acc[j4].w;
    }
    psq += bfly_sum64(st);
  }
  __shared__ float red[512];
  red[threadIdx.x] = psum; red[256 + threadIdx.x] = psq;
  __syncthreads();
  const int t = threadIdx.x;
  if (t < 64) {
    const float s0 = red[t] + red[t+64] + red[t+128] + red[t+192];
    const float q0 = red[256+t] + red[256+t+64] + red[256+t+128] + red[256+t+192];
    float* stat = (float*)((char*)P.ws + OFF_STATS) + (size_t)(128 + t)*16;
    atomicAdd(stat, s0); atomicAdd(stat + 8, q0);
  }
}

template<bool LOADX2>
__global__ __launch_bounds__(256) void k_layer3(Ptrs P) {
  const float* params = (const float*)((const char*)P.ws + OFF_PARAMS);
  const float* sc1 = params, *sh1 = params + 128;
  const float* sc2 = params + 256, *sh2 = params + 320;
  float psum = 0.0f, psq = 0.0f;
  const unsigned stride = gridDim.x * 256;
  for (unsigned s = blockIdx.x*256 + threadIdx.x; s < BATCH; s += stride) {
    float4 acc3[8];
    if (LOADX2) {
      const float* x2g = (const float*)((const char*)P.ws + OFF_X2);
      #pragma unroll
      for (int j4 = 0; j4 < 8; ++j4) acc3[j4] = ld4(P.b3 + j4*4);
      #pragma unroll 1
      for (int k = 0; k < 64; ++k) {
        const float hk = fmaxf(fmaf(x2g[(size_t)k*BATCH + s], sc2[k], sh2[k]), 0.0f);
        const float4* wrow = reinterpret_cast<const float4*>(P.W3 + k*32);
        #pragma unroll
        for (int j4 = 0; j4 < 8; ++j4) fma4s(acc3[j4], wrow[j4], hk);
      }
    } else {
      const SIn si = load_sample(P, s);
      float4 acc2[16];
      compute_x2(si, P, sc1, sh1, acc2);
      x3_from_acc2(acc2, P, sc2, sh2, acc3);
    }
    if (LOADX2) {
      float* x3g = (float*)((char*)P.ws + OFF_X3);
      #pragma unroll
      for (int j4 = 0; j4 < 8; ++j4) {
        x3g[(size_t)(j4*4+0)*BATCH + s] = acc3[j4].x;
        x3g[(size_t)(j4*4+1)*BATCH + s] = acc3[j4].y;
        x3g[(size_t)(j4*4+2)*BATCH + s] = acc3[j4].z;
        x3g[(size_t)(j4*4+3)*BATCH + s] = acc3[j4].w;
      }
    }
    float st[64];
    #pragma unroll
    for (int j4 = 0; j4 < 8; ++j4) {
      st[4*j4+0] = acc3[j4].x; st[4*j4+1] = acc3[j4].y;
      st[4*j4+2] = acc3[j4].z; st[4*j4+3] = acc3[j4].w;
    }
    #pragma unroll
    for (int i = 32; i < 64; ++i) st[i] = 0.0f;
    psum += bfly_sum64(st);
    #pragma unroll
    for (int j4 = 0; j4 < 8; ++j4) {
      st[4*j4+0] = acc3[j4].x*acc3[j4].x; st[4*j4+1] = acc3[j4].y*acc3[j4].y;
      st[4*j4+2] = acc3[j4].z*acc3[j4].z; st[4*j4+3] = acc3[j4].w*acc3[j4].w;
    }
    #pragma unroll
    for (int i = 32; i < 64; ++i) st[i] = 0.0f;
    psq += bfly_sum64(st);
  }
  __shared__ float red[512];
  red[threadIdx.x] = psum; red[256 + threadIdx.x] = psq;
  __syncthreads();
  const int t = threadIdx.x;
  if (t < 32) {
    const float s0 = red[t] + red[t+64] + red[t+128] + red[t+192];
    const float q0 = red[256+t] + red[256+t+64] + red[256+t+128] + red[256+t+192];
    float* stat = (float*)((char*)P.ws + OFF_STATS) + (size_t)(192 + t)*16;
    atomicAdd(stat, s0); atomicAdd(stat + 8, q0);
  }
}

template<bool LOADX3>
__global__ __launch_bounds__(256) void k_layer4(Ptrs P) {
  const float* params = (const float*)((const char*)P.ws + OFF_PARAMS);
  const float* sc1 = params, *sh1 = params + 128;
  const float* sc2 = params + 256, *sh2 = params + 320;
  const float* sc3 = params + 384, *sh3 = params + 416;
  const unsigned stride = gridDim.x * 256;
  for (unsigned s = blockIdx.x*256 + threadIdx.x; s < BATCH; s += stride) {
    float z = P.b4[0];
    if (LOADX3) {
      const float* x3g = (const float*)((const char*)P.ws + OFF_X3);
      #pragma unroll 1
      for (int k = 0; k < 32; ++k) {
        const float hk = fmaxf(fmaf(x3g[(size_t)k*BATCH + s], sc3[k], sh3[k]), 0.0f);
        z = fmaf(hk, P.W4[k], z);
      }
    } else {
      const SIn si = load_sample(P, s);
      float4 acc2[16];
      compute_x2(si, P, sc1, sh1, acc2);
      float4 acc3[8];
      x3_from_acc2(acc2, P, sc2, sh2, acc3);
      #pragma unroll
      for (int k4 = 0; k4 < 8; ++k4) {
        const float4 a = acc3[k4];
        const float4 sc = ld4(sc3 + k4*4), sh = ld4(sh3 + k4*4);
        z = fmaf(fmaxf(fmaf(a.x, sc.x, sh.x), 0.0f), P.W4[k4*4+0], z);
        z = fmaf(fmaxf(fmaf(a.y, sc.y, sh.y), 0.0f), P.W4[k4*4+1], z);
        z = fmaf(fmaxf(fmaf(a.z, sc.z, sh.z), 0.0f), P.W4[k4*4+2], z);
        z = fmaf(fmaxf(fmaf(a.w, sc.w, sh.w), 0.0f), P.W4[k4*4+3], z);
      }
    }
    P.out[s] = 1.0f / (1.0f + __expf(-z));
  }
}

// ---------------- host ----------------

extern "C" void kernel_launch(void* const* d_in, const int* in_sizes, int n_in,
                              void* d_out, int out_size, void* d_ws, size_t ws_size,
                              hipStream_t stream) {
  Ptrs P;
  P.br1 = (const int*)d_in[0];  P.sz1 = (const int*)d_in[1];
  P.en1 = (const int*)d_in[2];  P.tp1 = (const int*)d_in[3];
  P.ag1 = (const float*)d_in[4]; P.so1 = (const float*)d_in[5]; P.wt1 = (const float*)d_in[6];
  P.br2 = (const int*)d_in[7];  P.sz2 = (const int*)d_in[8];
  P.en2 = (const int*)d_in[9];  P.tp2 = (const int*)d_in[10];
  P.ag2 = (const float*)d_in[11]; P.so2 = (const float*)d_in[12]; P.wt2 = (const float*)d_in[13];
  P.bemb = (const float*)d_in[14]; P.temb = (const float*)d_in[15];
  P.W1 = (const float*)d_in[16]; P.b1 = (const float*)d_in[17];
  P.g1 = (const float*)d_in[18]; P.be1 = (const float*)d_in[19];
  P.W2 = (const float*)d_in[20]; P.b2 = (const float*)d_in[21];
  P.g2 = (const float*)d_in[22]; P.be2 = (const float*)d_in[23];
  P.W3 = (const float*)d_in[24]; P.b3 = (const float*)d_in[25];
  P.g3 = (const float*)d_in[26]; P.be3 = (const float*)d_in[27];
  P.W4 = (const float*)d_in[28]; P.b4 = (const float*)d_in[29];
  P.ws = (float*)d_ws; P.out = (float*)d_out;

  const bool store = (ws_size >= WS_NEED);

  hipMemsetAsync((char*)d_ws + OFF_STATS, 0, 224*64, stream);
  hipLaunchKernelGGL(k_tables, dim3(1), dim3(128), 0, stream, P);
  hipLaunchKernelGGL(k_stats1, dim3(2048), dim3(256), 0, stream, P);
  hipLaunchKernelGGL(k_finalize, dim3(1), dim3(128), 0, stream, P, 128, 0, 0, P.g1, P.be1);
  if (store) {
    hipLaunchKernelGGL((k_layer2<true>),  dim3(2048), dim3(256), 0, stream, P);
    hipLaunchKernelGGL(k_finalize, dim3(1), dim3(64), 0, stream, P, 64, 128, 256, P.g2, P.be2);
    hipLaunchKernelGGL((k_layer3<true>),  dim3(2048), dim3(256), 0, stream, P);
    hipLaunchKernelGGL(k_finalize, dim3(1), dim3(32), 0, stream, P, 32, 192, 384, P.g3, P.be3);
    hipLaunchKernelGGL((k_layer4<true>),  dim3(2048), dim3(256), 0, stream, P);
  } else {
    hipLaunchKernelGGL((k_layer2<false>), dim3(2048), dim3(256), 0, stream, P);
    hipLaunchKernelGGL(k_finalize, dim3(1), dim3(64), 0, stream, P, 64, 128, 256, P.g2, P.be2);
    hipLaunchKernelGGL((k_layer3<false>), dim3(2048), dim3(256), 0, stream, P);
    hipLaunchKernelGGL(k_finalize, dim3(1), dim3(32), 0, stream, P, 32, 192, 384, P.g3, P.be3);
    hipLaunchKernelGGL((k_layer4<false>), dim3(2048), dim3(256), 0, stream, P);
  }
}